// Round 16
// baseline (759.615 us; speedup 1.0000x reference)
//
#include <hip/hip_runtime.h>
#include <hip/hip_fp16.h>

#define D    300
#define DC   75    // valid D/4 chunks per row
#define PNL  8     // panels (one per XCD)
#define PCH  10    // chunks per panel per row (80 chunks; 75 valid)
#define SLOTS 6    // edge slots per wave (6*10 = 60 active lanes)
#define RW   25    // rows per wave in gather
#define SCB  1024  // scan block size

typedef _Float16 half4v __attribute__((ext_vector_type(4)));

// ---------------- embedding -> fp16 h0, panel-major [PNL][N][PCH] ----------------
__global__ __launch_bounds__(256) void embed_panel(const int* __restrict__ x,
                                                   const float4* __restrict__ atomT,
                                                   const float4* __restrict__ wordT,
                                                   half4v* __restrict__ h, int N) {
    int bid = blockIdx.x;
    int p = bid & 7;
    int chunk = (bid >> 3) * 256 + threadIdx.x;
    if (chunk >= N * PCH) return;
    int n = chunk / PCH, cc = chunk - n * PCH;
    int c_lin = p * PCH + cc;
    half4v o = (half4v)(_Float16)0;
    if (c_lin < DC) {
        int a = x[n * 2 + 0];
        int w = x[n * 2 + 1];
        float4 va = atomT[(size_t)a * DC + c_lin];
        float4 vw = wordT[(size_t)w * DC + c_lin];
        o[0] = (_Float16)(va.x + vw.x);
        o[1] = (_Float16)(va.y + vw.y);
        o[2] = (_Float16)(va.z + vw.z);
        o[3] = (_Float16)(va.w + vw.w);
    }
    h[(size_t)p * N * PCH + chunk] = o;   // normal store: warms panel XCD's L2
}

// ---------------- CSR build ----------------
__global__ __launch_bounds__(256) void cnt_kernel(const int* __restrict__ dst, int* __restrict__ cnt, int E) {
    int i = blockIdx.x * blockDim.x + threadIdx.x;
    if (i < E) atomicAdd(&cnt[dst[i]], 1);
}
__global__ __launch_bounds__(SCB) void scan1_kernel(const int* __restrict__ cnt,
                                                    int* __restrict__ off, int* __restrict__ bsum,
                                                    float* __restrict__ dinv, int N) {
    __shared__ int warp_sums[16];
    const int tid = threadIdx.x;
    const int lane = tid & 63;
    const int wid = tid >> 6;
    int i = blockIdx.x * SCB + tid;
    int v = (i < N) ? cnt[i] : 0;
    if (i < N) dinv[i] = rsqrtf((float)(v + 1));   // +1 self-loop
    int s = v;
    #pragma unroll
    for (int d = 1; d < 64; d <<= 1) {
        int t = __shfl_up(s, d, 64);
        if (lane >= d) s += t;
    }
    if (lane == 63) warp_sums[wid] = s;
    __syncthreads();
    if (wid == 0) {
        int ws = (lane < 16) ? warp_sums[lane] : 0;
        #pragma unroll
        for (int d = 1; d < 16; d <<= 1) {
            int t = __shfl_up(ws, d, 64);
            if (lane >= d) ws += t;
        }
        if (lane < 16) warp_sums[lane] = ws;
    }
    __syncthreads();
    int excl = (wid ? warp_sums[wid - 1] : 0) + s - v;
    if (i < N) off[i] = excl;
    if (tid == SCB - 1) bsum[blockIdx.x] = warp_sums[15];
}
__global__ __launch_bounds__(SCB) void scan2_kernel(int* __restrict__ bsum, int* __restrict__ bbase,
                                                    int* __restrict__ off, int nb, int N, int E) {
    __shared__ int warp_sums[16];
    const int tid = threadIdx.x;
    const int lane = tid & 63;
    const int wid = tid >> 6;
    int v = (tid < nb) ? bsum[tid] : 0;
    int s = v;
    #pragma unroll
    for (int d = 1; d < 64; d <<= 1) {
        int t = __shfl_up(s, d, 64);
        if (lane >= d) s += t;
    }
    if (lane == 63) warp_sums[wid] = s;
    __syncthreads();
    if (wid == 0) {
        int ws = (lane < 16) ? warp_sums[lane] : 0;
        #pragma unroll
        for (int d = 1; d < 16; d <<= 1) {
            int t = __shfl_up(ws, d, 64);
            if (lane >= d) ws += t;
        }
        if (lane < 16) warp_sums[lane] = ws;
    }
    __syncthreads();
    if (tid < nb) bbase[tid] = (wid ? warp_sums[wid - 1] : 0) + s - v;
    if (tid == 0) off[N] = E;
}
__global__ __launch_bounds__(256) void scan3_kernel(int* __restrict__ off, const int* __restrict__ bbase,
                                                    int* __restrict__ cursor, int N) {
    int i = blockIdx.x * blockDim.x + threadIdx.x;
    if (i >= N) return;
    int o = off[i] + bbase[i >> 10];
    off[i] = o;
    cursor[i] = o;
}
__global__ __launch_bounds__(256) void fill_kernel(const int* __restrict__ src, const int* __restrict__ dst,
                                                   const float* __restrict__ dinv, int* __restrict__ cursor,
                                                   int* __restrict__ csr_src, float* __restrict__ csr_w, int E) {
    int e = blockIdx.x * blockDim.x + threadIdx.x;
    if (e >= E) return;
    int s = src[e], d = dst[e];
    int slot = atomicAdd(&cursor[d], 1);
    csr_src[slot] = s;
    csr_w[slot] = dinv[s] * dinv[d];
}
__global__ __launch_bounds__(256) void seg_start_kernel(const int* __restrict__ batch,
                                                        int* __restrict__ start, int N, int G) {
    int i = blockIdx.x * blockDim.x + threadIdx.x;
    if (i >= N) return;
    int b = batch[i];
    int prev = (i == 0) ? -1 : batch[i - 1];
    for (int g = prev + 1; g <= b; ++g) start[g] = i;
    if (i == N - 1)
        for (int g = b + 1; g <= G; ++g) start[g] = N;
}

// ---------------- W-prep (2 kernels, fp32) ----------------
__global__ __launch_bounds__(256) void wprep1(const float* __restrict__ W, const float* __restrict__ bias,
                                              float* __restrict__ W2, float* __restrict__ w1b) {
    int bid = blockIdx.x;
    if (bid < 352) {
        int id = bid * 256 + threadIdx.x;
        if (id >= D * D) return;
        int i = id / D, j = id % D;
        float acc = 0.f;
        #pragma unroll 4
        for (int k = 0; k < D; ++k) acc = fmaf(W[i * D + k], W[k * D + j], acc);
        W2[id] = acc;
    } else {
        int j = threadIdx.x;
        if (j >= D) return;
        float acc = 0.f;
        #pragma unroll 4
        for (int k = 0; k < D; ++k) acc = fmaf(bias[k], W[k * D + j], acc);
        w1b[j] = acc;
    }
}
__global__ __launch_bounds__(256) void wprep2(const float* __restrict__ W2, const float* __restrict__ W,
                                              const float* __restrict__ w1b,
                                              float* __restrict__ W4, float* __restrict__ w2b,
                                              float* __restrict__ w3b) {
    int bid = blockIdx.x;
    if (bid < 352) {
        int id = bid * 256 + threadIdx.x;
        if (id >= D * D) return;
        int i = id / D, j = id % D;
        float acc = 0.f;
        #pragma unroll 4
        for (int k = 0; k < D; ++k) acc = fmaf(W2[i * D + k], W2[k * D + j], acc);
        W4[id] = acc;
    } else if (bid == 352) {
        int j = threadIdx.x;
        if (j >= D) return;
        float acc = 0.f;
        #pragma unroll 4
        for (int k = 0; k < D; ++k) acc = fmaf(w1b[k], W[k * D + j], acc);
        w2b[j] = acc;
    } else {
        int j = threadIdx.x;
        if (j >= D) return;
        float acc = 0.f;
        #pragma unroll 4
        for (int k = 0; k < D; ++k) acc = fmaf(w1b[k], W2[k * D + j], acc);
        w3b[j] = acc;
    }
}

// ---------------- uniform slot-parallel panel gather ----------------
// Wave = 6 slots x 10 chunks (lanes 60-63 idle). One row at a time, RW rows/wave.
// j0/j1 wave-uniform -> no divergence; slot s takes edges j0+s, j0+s+6, ...
// Cross-slot reduce: 3-step shfl tree (lanes 0-9 hold the result).
__global__ __launch_bounds__(256) void gather_panel_u(const half4v* __restrict__ in,
                                                      const int* __restrict__ off,
                                                      const int* __restrict__ csr_src,
                                                      const float* __restrict__ csr_w,
                                                      const float* __restrict__ dinv,
                                                      const float* __restrict__ uin,
                                                      float* __restrict__ uout,
                                                      half4v* __restrict__ out, int N) {
    const int bid = blockIdx.x;
    const int p = bid & 7;                       // panel == XCD round-robin
    const int lane = threadIdx.x & 63;
    const int wib = threadIdx.x >> 6;
    const int slot = lane / PCH;                 // 0..6 (6 => idle)
    const int cc = lane - slot * PCH;
    const bool active = slot < SLOTS;
    const bool dou = (uout != nullptr) && (p == 0);

    const half4v* pin  = in  + (size_t)p * N * PCH;
    half4v*       pout = out + (size_t)p * N * PCH;

    int row0 = ((bid >> 3) * 4 + wib) * RW;
    if (row0 >= N) return;
    int rowEnd = min(row0 + RW, N);

    int j0 = __builtin_nontemporal_load(&off[row0]);
    for (int n = row0; n < rowEnd; ++n) {
        int j1 = __builtin_nontemporal_load(&off[n + 1]);
        float s = dinv[n]; s = s * s;

        float4 acc = make_float4(0.f, 0.f, 0.f, 0.f);
        float uacc = 0.f;
        if (active && slot == 0) {
            half4v v0 = pin[(size_t)n * PCH + cc];
            acc.x = s * (float)v0[0]; acc.y = s * (float)v0[1];
            acc.z = s * (float)v0[2]; acc.w = s * (float)v0[3];
            if (dou && cc == 0) uacc = s * (uin ? uin[n] : 1.0f);
        }
        if (active) {
            for (int j = j0 + slot; j < j1; j += SLOTS) {
                int sn = __builtin_nontemporal_load(&csr_src[j]);
                float w = __builtin_nontemporal_load(&csr_w[j]);
                half4v u = pin[(size_t)sn * PCH + cc];   // L2-resident panel row
                acc.x += w * (float)u[0]; acc.y += w * (float)u[1];
                acc.z += w * (float)u[2]; acc.w += w * (float)u[3];
                if (dou && cc == 0) uacc += w * (uin ? uin[sn] : 1.0f);
            }
        }
        // slot reduction: r1 = acc + acc(lane+30); total = r1 + r1(+10) + r1(+20)
        float4 r1;
        r1.x = acc.x + __shfl(acc.x, lane + 30, 64);
        r1.y = acc.y + __shfl(acc.y, lane + 30, 64);
        r1.z = acc.z + __shfl(acc.z, lane + 30, 64);
        r1.w = acc.w + __shfl(acc.w, lane + 30, 64);
        float4 tot;
        tot.x = r1.x + __shfl(r1.x, lane + 10, 64) + __shfl(r1.x, lane + 20, 64);
        tot.y = r1.y + __shfl(r1.y, lane + 10, 64) + __shfl(r1.y, lane + 20, 64);
        tot.z = r1.z + __shfl(r1.z, lane + 10, 64) + __shfl(r1.z, lane + 20, 64);
        tot.w = r1.w + __shfl(r1.w, lane + 10, 64) + __shfl(r1.w, lane + 20, 64);
        if (dou) {
            float u1r = uacc + __shfl(uacc, lane + 30, 64);
            float ut  = u1r + __shfl(u1r, lane + 10, 64) + __shfl(u1r, lane + 20, 64);
            if (lane == 0) uout[n] = ut;
        }
        if (slot == 0) {
            half4v o;
            o[0] = (_Float16)tot.x; o[1] = (_Float16)tot.y;
            o[2] = (_Float16)tot.z; o[3] = (_Float16)tot.w;
            __builtin_nontemporal_store(o, &pout[(size_t)n * PCH + cc]);
        }
        j0 = j1;
    }
}

// ---------------- pool g4 + u's per graph (panel-major input) ----------------
__global__ __launch_bounds__(256) void pool_seg(const half4v* __restrict__ g4,
                                                const float* __restrict__ u1,
                                                const float* __restrict__ u2,
                                                const float* __restrict__ u3,
                                                const int* __restrict__ start,
                                                float* __restrict__ pg4, float* __restrict__ pu,
                                                int G, int N) {
    int g = blockIdx.x;
    if (g >= G) return;
    int j0 = start[g], j1 = start[g + 1];
    float inv = (j1 > j0) ? 1.0f / (float)(j1 - j0) : 0.0f;
    int tid = threadIdx.x;
    if (tid < PNL * PCH) {
        int p = tid / PCH, cc = tid - p * PCH;
        int c_lin = p * PCH + cc;
        if (c_lin < DC) {
            const half4v* pg = g4 + (size_t)p * N * PCH;
            float4 acc = make_float4(0.f, 0.f, 0.f, 0.f);
            for (int n = j0; n < j1; ++n) {
                half4v v = pg[(size_t)n * PCH + cc];
                acc.x += (float)v[0]; acc.y += (float)v[1];
                acc.z += (float)v[2]; acc.w += (float)v[3];
            }
            float4 o = make_float4(acc.x * inv, acc.y * inv, acc.z * inv, acc.w * inv);
            *(float4*)&pg4[(size_t)g * D + c_lin * 4] = o;
        }
    } else if (tid >= 80 && tid <= 82) {
        const float* u = (tid == 80) ? u1 : (tid == 81) ? u2 : u3;
        float acc = 0.f;
        for (int n = j0; n < j1; ++n) acc += u[n];
        pu[g * 4 + (tid - 80)] = acc * inv;
    } else if (tid == 83) {
        pu[g * 4 + 3] = (j1 > j0) ? 1.0f : 0.0f;
    }
}

// ---------------- final small GEMM (fp32, exact) ----------------
__global__ __launch_bounds__(256) void final_small(const float* __restrict__ pg4,
                                                   const float* __restrict__ pu,
                                                   const float* __restrict__ W4,
                                                   const float* __restrict__ w1b,
                                                   const float* __restrict__ w2b,
                                                   const float* __restrict__ w3b,
                                                   const float* __restrict__ bias,
                                                   float* __restrict__ out, int G) {
    __shared__ float row[D];
    int g = blockIdx.x;
    if (g >= G) return;
    int tid = threadIdx.x;
    for (int c = tid; c < D; c += 256) row[c] = pg4[(size_t)g * D + c];
    __syncthreads();
    float p1 = pu[g * 4 + 0], p2 = pu[g * 4 + 1], p3 = pu[g * 4 + 2], fl = pu[g * 4 + 3];
    for (int j = tid; j < D; j += 256) {
        float acc = 0.f;
        #pragma unroll 4
        for (int k = 0; k < D; ++k) acc = fmaf(row[k], W4[(size_t)k * D + j], acc);
        out[(size_t)g * D + j] = acc + p1 * w1b[j] + p2 * w2b[j] + p3 * w3b[j] + fl * bias[j];
    }
}

extern "C" void kernel_launch(void* const* d_in, const int* in_sizes, int n_in,
                              void* d_out, int out_size, void* d_ws, size_t ws_size,
                              hipStream_t stream) {
    (void)n_in; (void)ws_size;
    const int*   x     = (const int*)d_in[0];
    const int*   ei    = (const int*)d_in[1];
    const int*   batch = (const int*)d_in[2];
    // d_in[3] = num_hops (fixed 4)
    const float* atomT = (const float*)d_in[4];
    const float* wordT = (const float*)d_in[5];
    const float* W     = (const float*)d_in[6];
    const float* bias  = (const float*)d_in[7];

    const int N = in_sizes[0] / 2;
    const int E = in_sizes[1] / 2;
    const int G = out_size / D;

    const int* src = ei;
    const int* dst = ei + E;

    // workspace layout
    _Float16* fA16   = (_Float16*)d_ws;                   // PNL*N*PCH*4 fp16
    _Float16* fB16   = fA16 + (size_t)PNL * N * PCH * 4;  // PNL*N*PCH*4 fp16
    float*    dinv   = (float*)(fB16 + (size_t)PNL * N * PCH * 4); // N
    float*    csr_w  = dinv + N;                          // E
    float*    W2     = csr_w + E;                         // D*D
    float*    W4     = W2 + D * D;                        // D*D
    float*    w1b    = W4 + D * D;                        // D
    float*    w2b    = w1b + D;                           // D
    float*    w3b    = w2b + D;                           // D
    float*    u1     = w3b + D;                           // N
    float*    u2     = u1 + N;                            // N
    float*    u3     = u2 + N;                            // N
    float*    pg4    = u3 + N;                            // G*D
    float*    pu     = pg4 + (size_t)G * D;               // 4*G
    int*      cnt    = (int*)(pu + 4 * G);                // N
    int*      off    = cnt + N;                           // N+1
    int*      cursor = off + N + 1;                       // N
    int*      csr_src= cursor + N;                        // E
    int*      bsum   = csr_src + E;                       // <=1024
    int*      bbase  = bsum + 1024;                       // <=1024
    int*      start  = bbase + 1024;                      // G+1

    const int B = 256;
    const int nBlocks  = (N + B - 1) / B;
    const int nbScan   = (N + SCB - 1) / SCB;
    const int nbPanelE = (N * PCH + B - 1) / B;           // embed blocks per panel
    const int embedGrid = nbPanelE * PNL;

    // gather grid: ceil(N / (4 waves * RW)) blocks per panel, x8 panels
    const int gBlocksPerPanel = (N + 4 * RW - 1) / (4 * RW);
    const int gatherGrid = gBlocksPerPanel * PNL;

    embed_panel<<<embedGrid, B, 0, stream>>>(x, (const float4*)atomT, (const float4*)wordT,
                                             (half4v*)fA16, N);

    hipMemsetAsync(cnt, 0, (size_t)N * sizeof(int), stream);
    cnt_kernel<<<(E + B - 1) / B, B, 0, stream>>>(dst, cnt, E);
    scan1_kernel<<<nbScan, SCB, 0, stream>>>(cnt, off, bsum, dinv, N);
    scan2_kernel<<<1, SCB, 0, stream>>>(bsum, bbase, off, nbScan, N, E);
    scan3_kernel<<<nBlocks, B, 0, stream>>>(off, bbase, cursor, N);
    fill_kernel<<<(E + B - 1) / B, B, 0, stream>>>(src, dst, dinv, cursor, csr_src, csr_w, E);
    seg_start_kernel<<<nBlocks, B, 0, stream>>>(batch, start, N, G);

    wprep1<<<353, B, 0, stream>>>(W, bias, W2, w1b);
    wprep2<<<354, B, 0, stream>>>(W2, W, w1b, W4, w2b, w3b);

    // g_k = A_hat^k h0 (panel ping-pong), u_k fused into passes 1-3 (panel 0)
    gather_panel_u<<<gatherGrid, B, 0, stream>>>((const half4v*)fA16, off, csr_src, csr_w, dinv,
                                                 nullptr, u1, (half4v*)fB16, N);
    gather_panel_u<<<gatherGrid, B, 0, stream>>>((const half4v*)fB16, off, csr_src, csr_w, dinv,
                                                 u1, u2, (half4v*)fA16, N);
    gather_panel_u<<<gatherGrid, B, 0, stream>>>((const half4v*)fA16, off, csr_src, csr_w, dinv,
                                                 u2, u3, (half4v*)fB16, N);
    gather_panel_u<<<gatherGrid, B, 0, stream>>>((const half4v*)fB16, off, csr_src, csr_w, dinv,
                                                 nullptr, nullptr, (half4v*)fA16, N);

    pool_seg<<<G, B, 0, stream>>>((const half4v*)fA16, u1, u2, u3, start, pg4, pu, G, N);
    final_small<<<G, B, 0, stream>>>(pg4, pu, W4, w1b, w2b, w3b, bias, (float*)d_out, G);
}

// Round 17
// 375.463 us; speedup vs baseline: 2.0231x; 2.0231x over previous
//
#include <hip/hip_runtime.h>
#include <hip/hip_fp16.h>

#define D    300
#define DC   75    // D/4 half4 chunks per row
#define SCB  1024  // scan block size

typedef _Float16 half4v __attribute__((ext_vector_type(4)));

// ---------------- embedding -> fp16 h0 (compact N x D) ----------------
__global__ __launch_bounds__(256) void embed_f16(const int* __restrict__ x,
                                                 const float4* __restrict__ atomT,
                                                 const float4* __restrict__ wordT,
                                                 half4v* __restrict__ h, int N) {
    int idx = blockIdx.x * blockDim.x + threadIdx.x;
    if (idx >= N * DC) return;
    int n = idx / DC, c = idx - n * DC;
    int a = x[n * 2 + 0];
    int w = x[n * 2 + 1];
    float4 va = atomT[(size_t)a * DC + c];
    float4 vw = wordT[(size_t)w * DC + c];
    half4v o;
    o[0] = (_Float16)(va.x + vw.x);
    o[1] = (_Float16)(va.y + vw.y);
    o[2] = (_Float16)(va.z + vw.z);
    o[3] = (_Float16)(va.w + vw.w);
    h[idx] = o;
}

// ---------------- CSR build ----------------
__global__ __launch_bounds__(256) void cnt_kernel(const int* __restrict__ dst, int* __restrict__ cnt, int E) {
    int i = blockIdx.x * blockDim.x + threadIdx.x;
    if (i < E) atomicAdd(&cnt[dst[i]], 1);
}
__global__ __launch_bounds__(SCB) void scan1_kernel(const int* __restrict__ cnt,
                                                    int* __restrict__ off, int* __restrict__ bsum,
                                                    float* __restrict__ dinv, int N) {
    __shared__ int warp_sums[16];
    const int tid = threadIdx.x;
    const int lane = tid & 63;
    const int wid = tid >> 6;
    int i = blockIdx.x * SCB + tid;
    int v = (i < N) ? cnt[i] : 0;
    if (i < N) dinv[i] = rsqrtf((float)(v + 1));   // +1 self-loop
    int s = v;
    #pragma unroll
    for (int d = 1; d < 64; d <<= 1) {
        int t = __shfl_up(s, d, 64);
        if (lane >= d) s += t;
    }
    if (lane == 63) warp_sums[wid] = s;
    __syncthreads();
    if (wid == 0) {
        int ws = (lane < 16) ? warp_sums[lane] : 0;
        #pragma unroll
        for (int d = 1; d < 16; d <<= 1) {
            int t = __shfl_up(ws, d, 64);
            if (lane >= d) ws += t;
        }
        if (lane < 16) warp_sums[lane] = ws;
    }
    __syncthreads();
    int excl = (wid ? warp_sums[wid - 1] : 0) + s - v;
    if (i < N) off[i] = excl;
    if (tid == SCB - 1) bsum[blockIdx.x] = warp_sums[15];
}
__global__ __launch_bounds__(SCB) void scan2_kernel(int* __restrict__ bsum, int* __restrict__ bbase,
                                                    int* __restrict__ off, int nb, int N, int E) {
    __shared__ int warp_sums[16];
    const int tid = threadIdx.x;
    const int lane = tid & 63;
    const int wid = tid >> 6;
    int v = (tid < nb) ? bsum[tid] : 0;
    int s = v;
    #pragma unroll
    for (int d = 1; d < 64; d <<= 1) {
        int t = __shfl_up(s, d, 64);
        if (lane >= d) s += t;
    }
    if (lane == 63) warp_sums[wid] = s;
    __syncthreads();
    if (wid == 0) {
        int ws = (lane < 16) ? warp_sums[lane] : 0;
        #pragma unroll
        for (int d = 1; d < 16; d <<= 1) {
            int t = __shfl_up(ws, d, 64);
            if (lane >= d) ws += t;
        }
        if (lane < 16) warp_sums[lane] = ws;
    }
    __syncthreads();
    if (tid < nb) bbase[tid] = (wid ? warp_sums[wid - 1] : 0) + s - v;
    if (tid == 0) off[N] = E;   // sum of cnt == E identically
}
__global__ __launch_bounds__(256) void scan3_kernel(int* __restrict__ off, const int* __restrict__ bbase,
                                                    int* __restrict__ cursor, int N) {
    int i = blockIdx.x * blockDim.x + threadIdx.x;
    if (i >= N) return;
    int o = off[i] + bbase[i >> 10];
    off[i] = o;
    cursor[i] = o;
}
__global__ __launch_bounds__(256) void fill_kernel(const int* __restrict__ src, const int* __restrict__ dst,
                                                   const float* __restrict__ dinv, int* __restrict__ cursor,
                                                   int* __restrict__ csr_src, float* __restrict__ csr_w, int E) {
    int e = blockIdx.x * blockDim.x + threadIdx.x;
    if (e >= E) return;
    int s = src[e], d = dst[e];
    int slot = atomicAdd(&cursor[d], 1);
    csr_src[slot] = s;
    csr_w[slot] = dinv[s] * dinv[d];
}
__global__ __launch_bounds__(256) void seg_start_kernel(const int* __restrict__ batch,
                                                        int* __restrict__ start, int N, int G) {
    int i = blockIdx.x * blockDim.x + threadIdx.x;
    if (i >= N) return;
    int b = batch[i];
    int prev = (i == 0) ? -1 : batch[i - 1];
    for (int g = prev + 1; g <= b; ++g) start[g] = i;
    if (i == N - 1)
        for (int g = b + 1; g <= G; ++g) start[g] = N;
}

// ---------------- W-prep (2 kernels, fp32) ----------------
__global__ __launch_bounds__(256) void wprep1(const float* __restrict__ W, const float* __restrict__ bias,
                                              float* __restrict__ W2, float* __restrict__ w1b) {
    int bid = blockIdx.x;
    if (bid < 352) {
        int id = bid * 256 + threadIdx.x;
        if (id >= D * D) return;
        int i = id / D, j = id % D;
        float acc = 0.f;
        #pragma unroll 4
        for (int k = 0; k < D; ++k) acc = fmaf(W[i * D + k], W[k * D + j], acc);
        W2[id] = acc;
    } else {
        int j = threadIdx.x;
        if (j >= D) return;
        float acc = 0.f;
        #pragma unroll 4
        for (int k = 0; k < D; ++k) acc = fmaf(bias[k], W[k * D + j], acc);
        w1b[j] = acc;
    }
}
__global__ __launch_bounds__(256) void wprep2(const float* __restrict__ W2, const float* __restrict__ W,
                                              const float* __restrict__ w1b,
                                              float* __restrict__ W4, float* __restrict__ w2b,
                                              float* __restrict__ w3b) {
    int bid = blockIdx.x;
    if (bid < 352) {
        int id = bid * 256 + threadIdx.x;
        if (id >= D * D) return;
        int i = id / D, j = id % D;
        float acc = 0.f;
        #pragma unroll 4
        for (int k = 0; k < D; ++k) acc = fmaf(W2[i * D + k], W2[k * D + j], acc);
        W4[id] = acc;
    } else if (bid == 352) {
        int j = threadIdx.x;
        if (j >= D) return;
        float acc = 0.f;
        #pragma unroll 4
        for (int k = 0; k < D; ++k) acc = fmaf(w1b[k], W[k * D + j], acc);
        w2b[j] = acc;
    } else {
        int j = threadIdx.x;
        if (j >= D) return;
        float acc = 0.f;
        #pragma unroll 4
        for (int k = 0; k < D; ++k) acc = fmaf(w1b[k], W2[k * D + j], acc);
        w3b[j] = acc;
    }
}

// ---------------- sparse hop (fp16 rows, compact), optional fused scalar-u ----------------
__global__ __launch_bounds__(256) void gather_f16(const half4v* __restrict__ in,
                                                  const int* __restrict__ off,
                                                  const int* __restrict__ csr_src,
                                                  const float* __restrict__ csr_w,
                                                  const float* __restrict__ dinv,
                                                  const float* __restrict__ uin,
                                                  float* __restrict__ uout,
                                                  half4v* __restrict__ out, int N) {
    int idx = blockIdx.x * blockDim.x + threadIdx.x;
    if (idx >= N * DC) return;
    int n = idx / DC, c = idx - n * DC;
    float s = dinv[n]; s = s * s;
    half4v v0 = in[idx];
    float4 acc = make_float4(s * (float)v0[0], s * (float)v0[1], s * (float)v0[2], s * (float)v0[3]);
    const bool dou = (uout != nullptr) && (c == 0);
    float uacc = 0.f;
    if (dou) uacc = s * (uin ? uin[n] : 1.0f);
    int j0 = off[n], j1 = off[n + 1];
    for (int j = j0; j < j1; ++j) {
        int sn = csr_src[j];
        float w = csr_w[j];
        half4v u = in[(size_t)sn * DC + c];
        acc.x += w * (float)u[0]; acc.y += w * (float)u[1];
        acc.z += w * (float)u[2]; acc.w += w * (float)u[3];
        if (dou) uacc += w * (uin ? uin[sn] : 1.0f);
    }
    half4v o;
    o[0] = (_Float16)acc.x; o[1] = (_Float16)acc.y;
    o[2] = (_Float16)acc.z; o[3] = (_Float16)acc.w;
    out[idx] = o;
    if (dou) uout[n] = uacc;
}

// ---------------- fused pool + final GEMM: one block per graph ----------------
// Phase A: segment-mean of g4 rows -> LDS row[300]; u-means -> LDS scalars.
// Phase B: out[g][j] = sum_k row[k]*W4[k][j] + p1*w1b + p2*w2b + p3*w3b + flag*bias.
__global__ __launch_bounds__(256) void pool_final(const half4v* __restrict__ g4,
                                                  const float* __restrict__ u1,
                                                  const float* __restrict__ u2,
                                                  const float* __restrict__ u3,
                                                  const int* __restrict__ start,
                                                  const float* __restrict__ W4,
                                                  const float* __restrict__ w1b,
                                                  const float* __restrict__ w2b,
                                                  const float* __restrict__ w3b,
                                                  const float* __restrict__ bias,
                                                  float* __restrict__ out, int G) {
    __shared__ float row[D];
    __shared__ float us[4];
    int g = blockIdx.x;
    if (g >= G) return;
    int j0 = start[g], j1 = start[g + 1];
    float inv = (j1 > j0) ? 1.0f / (float)(j1 - j0) : 0.0f;
    int tid = threadIdx.x;
    if (tid < DC) {
        float4 acc = make_float4(0.f, 0.f, 0.f, 0.f);
        for (int n = j0; n < j1; ++n) {
            half4v v = g4[(size_t)n * DC + tid];
            acc.x += (float)v[0]; acc.y += (float)v[1];
            acc.z += (float)v[2]; acc.w += (float)v[3];
        }
        row[tid * 4 + 0] = acc.x * inv;
        row[tid * 4 + 1] = acc.y * inv;
        row[tid * 4 + 2] = acc.z * inv;
        row[tid * 4 + 3] = acc.w * inv;
    } else if (tid >= 80 && tid <= 82) {
        const float* u = (tid == 80) ? u1 : (tid == 81) ? u2 : u3;
        float acc = 0.f;
        for (int n = j0; n < j1; ++n) acc += u[n];
        us[tid - 80] = acc * inv;
    } else if (tid == 83) {
        us[3] = (j1 > j0) ? 1.0f : 0.0f;
    }
    __syncthreads();
    float p1 = us[0], p2 = us[1], p3 = us[2], fl = us[3];
    for (int j = tid; j < D; j += 256) {
        float acc = 0.f;
        #pragma unroll 4
        for (int k = 0; k < D; ++k) acc = fmaf(row[k], W4[(size_t)k * D + j], acc);
        out[(size_t)g * D + j] = acc + p1 * w1b[j] + p2 * w2b[j] + p3 * w3b[j] + fl * bias[j];
    }
}

extern "C" void kernel_launch(void* const* d_in, const int* in_sizes, int n_in,
                              void* d_out, int out_size, void* d_ws, size_t ws_size,
                              hipStream_t stream) {
    (void)n_in; (void)ws_size;
    const int*   x     = (const int*)d_in[0];
    const int*   ei    = (const int*)d_in[1];
    const int*   batch = (const int*)d_in[2];
    // d_in[3] = num_hops (fixed 4)
    const float* atomT = (const float*)d_in[4];
    const float* wordT = (const float*)d_in[5];
    const float* W     = (const float*)d_in[6];
    const float* bias  = (const float*)d_in[7];

    const int N = in_sizes[0] / 2;
    const int E = in_sizes[1] / 2;
    const int G = out_size / D;

    const int* src = ei;
    const int* dst = ei + E;

    // workspace layout (16B-aligned starts)
    _Float16* fA16   = (_Float16*)d_ws;                  // N*D fp16
    _Float16* fB16   = fA16 + (size_t)N * D;             // N*D fp16
    float*    dinv   = (float*)(fB16 + (size_t)N * D);   // N
    float*    csr_w  = dinv + N;                         // E
    float*    W2     = csr_w + E;                        // D*D
    float*    W4     = W2 + D * D;                       // D*D
    float*    w1b    = W4 + D * D;                       // D
    float*    w2b    = w1b + D;                          // D
    float*    w3b    = w2b + D;                          // D
    float*    u1     = w3b + D;                          // N
    float*    u2     = u1 + N;                           // N
    float*    u3     = u2 + N;                           // N
    int*      cnt    = (int*)(u3 + N);                   // N
    int*      off    = cnt + N;                          // N+1
    int*      cursor = off + N + 1;                      // N
    int*      csr_src= cursor + N;                       // E
    int*      bsum   = csr_src + E;                      // <=1024
    int*      bbase  = bsum + 1024;                      // <=1024
    int*      start  = bbase + 1024;                     // G+1

    const int B = 256;
    const int ndBlocks = (N * DC + B - 1) / B;
    const int nBlocks  = (N + B - 1) / B;
    const int nbScan   = (N + SCB - 1) / SCB;

    embed_f16<<<ndBlocks, B, 0, stream>>>(x, (const float4*)atomT, (const float4*)wordT, (half4v*)fA16, N);

    hipMemsetAsync(cnt, 0, (size_t)N * sizeof(int), stream);
    cnt_kernel<<<(E + B - 1) / B, B, 0, stream>>>(dst, cnt, E);
    scan1_kernel<<<nbScan, SCB, 0, stream>>>(cnt, off, bsum, dinv, N);
    scan2_kernel<<<1, SCB, 0, stream>>>(bsum, bbase, off, nbScan, N, E);
    scan3_kernel<<<nBlocks, B, 0, stream>>>(off, bbase, cursor, N);
    fill_kernel<<<(E + B - 1) / B, B, 0, stream>>>(src, dst, dinv, cursor, csr_src, csr_w, E);
    seg_start_kernel<<<nBlocks, B, 0, stream>>>(batch, start, N, G);

    wprep1<<<353, B, 0, stream>>>(W, bias, W2, w1b);
    wprep2<<<354, B, 0, stream>>>(W2, W, w1b, W4, w2b, w3b);

    // g_k = A_hat^k h0 (fp16 ping-pong), u_k fused into passes 1-3
    gather_f16<<<ndBlocks, B, 0, stream>>>((const half4v*)fA16, off, csr_src, csr_w, dinv,
                                           nullptr, u1, (half4v*)fB16, N);
    gather_f16<<<ndBlocks, B, 0, stream>>>((const half4v*)fB16, off, csr_src, csr_w, dinv,
                                           u1, u2, (half4v*)fA16, N);
    gather_f16<<<ndBlocks, B, 0, stream>>>((const half4v*)fA16, off, csr_src, csr_w, dinv,
                                           u2, u3, (half4v*)fB16, N);
    gather_f16<<<ndBlocks, B, 0, stream>>>((const half4v*)fB16, off, csr_src, csr_w, dinv,
                                           nullptr, nullptr, (half4v*)fA16, N);

    // fused pool + exact-fp32 small GEMM
    pool_final<<<G, B, 0, stream>>>((const half4v*)fA16, u1, u2, u3, start,
                                    W4, w1b, w2b, w3b, bias, (float*)d_out, G);
}

// Round 18
// 339.926 us; speedup vs baseline: 2.2346x; 1.1045x over previous
//
#include <hip/hip_runtime.h>
#include <hip/hip_fp16.h>

#define D    300
#define DC   75    // D/4 half4 chunks per row
#define SCB  1024  // scan block size
#define PGRP 6     // row-groups in pool phase A (6*75 = 450 active threads)

typedef _Float16 half4v __attribute__((ext_vector_type(4)));

// ---------------- embedding -> fp16 h0 (compact N x D) ----------------
__global__ __launch_bounds__(256) void embed_f16(const int* __restrict__ x,
                                                 const float4* __restrict__ atomT,
                                                 const float4* __restrict__ wordT,
                                                 half4v* __restrict__ h, int N) {
    int idx = blockIdx.x * blockDim.x + threadIdx.x;
    if (idx >= N * DC) return;
    int n = idx / DC, c = idx - n * DC;
    int a = x[n * 2 + 0];
    int w = x[n * 2 + 1];
    float4 va = atomT[(size_t)a * DC + c];
    float4 vw = wordT[(size_t)w * DC + c];
    half4v o;
    o[0] = (_Float16)(va.x + vw.x);
    o[1] = (_Float16)(va.y + vw.y);
    o[2] = (_Float16)(va.z + vw.z);
    o[3] = (_Float16)(va.w + vw.w);
    h[idx] = o;
}

// ---------------- CSR build ----------------
__global__ __launch_bounds__(256) void cnt_kernel(const int* __restrict__ dst, int* __restrict__ cnt, int E) {
    int i = blockIdx.x * blockDim.x + threadIdx.x;
    if (i < E) atomicAdd(&cnt[dst[i]], 1);
}
__global__ __launch_bounds__(SCB) void scan1_kernel(const int* __restrict__ cnt,
                                                    int* __restrict__ off, int* __restrict__ bsum,
                                                    float* __restrict__ dinv, int N) {
    __shared__ int warp_sums[16];
    const int tid = threadIdx.x;
    const int lane = tid & 63;
    const int wid = tid >> 6;
    int i = blockIdx.x * SCB + tid;
    int v = (i < N) ? cnt[i] : 0;
    if (i < N) dinv[i] = rsqrtf((float)(v + 1));   // +1 self-loop
    int s = v;
    #pragma unroll
    for (int d = 1; d < 64; d <<= 1) {
        int t = __shfl_up(s, d, 64);
        if (lane >= d) s += t;
    }
    if (lane == 63) warp_sums[wid] = s;
    __syncthreads();
    if (wid == 0) {
        int ws = (lane < 16) ? warp_sums[lane] : 0;
        #pragma unroll
        for (int d = 1; d < 16; d <<= 1) {
            int t = __shfl_up(ws, d, 64);
            if (lane >= d) ws += t;
        }
        if (lane < 16) warp_sums[lane] = ws;
    }
    __syncthreads();
    int excl = (wid ? warp_sums[wid - 1] : 0) + s - v;
    if (i < N) off[i] = excl;
    if (tid == SCB - 1) bsum[blockIdx.x] = warp_sums[15];
}
__global__ __launch_bounds__(SCB) void scan2_kernel(int* __restrict__ bsum, int* __restrict__ bbase,
                                                    int* __restrict__ off, int nb, int N, int E) {
    __shared__ int warp_sums[16];
    const int tid = threadIdx.x;
    const int lane = tid & 63;
    const int wid = tid >> 6;
    int v = (tid < nb) ? bsum[tid] : 0;
    int s = v;
    #pragma unroll
    for (int d = 1; d < 64; d <<= 1) {
        int t = __shfl_up(s, d, 64);
        if (lane >= d) s += t;
    }
    if (lane == 63) warp_sums[wid] = s;
    __syncthreads();
    if (wid == 0) {
        int ws = (lane < 16) ? warp_sums[lane] : 0;
        #pragma unroll
        for (int d = 1; d < 16; d <<= 1) {
            int t = __shfl_up(ws, d, 64);
            if (lane >= d) ws += t;
        }
        if (lane < 16) warp_sums[lane] = ws;
    }
    __syncthreads();
    if (tid < nb) bbase[tid] = (wid ? warp_sums[wid - 1] : 0) + s - v;
    if (tid == 0) off[N] = E;   // sum of cnt == E identically
}
__global__ __launch_bounds__(256) void scan3_kernel(int* __restrict__ off, const int* __restrict__ bbase,
                                                    int* __restrict__ cursor, int N) {
    int i = blockIdx.x * blockDim.x + threadIdx.x;
    if (i >= N) return;
    int o = off[i] + bbase[i >> 10];
    off[i] = o;
    cursor[i] = o;
}
__global__ __launch_bounds__(256) void fill_kernel(const int* __restrict__ src, const int* __restrict__ dst,
                                                   const float* __restrict__ dinv, int* __restrict__ cursor,
                                                   int* __restrict__ csr_src, float* __restrict__ csr_w, int E) {
    int e = blockIdx.x * blockDim.x + threadIdx.x;
    if (e >= E) return;
    int s = src[e], d = dst[e];
    int slot = atomicAdd(&cursor[d], 1);
    csr_src[slot] = s;
    csr_w[slot] = dinv[s] * dinv[d];
}
__global__ __launch_bounds__(256) void seg_start_kernel(const int* __restrict__ batch,
                                                        int* __restrict__ start, int N, int G) {
    int i = blockIdx.x * blockDim.x + threadIdx.x;
    if (i >= N) return;
    int b = batch[i];
    int prev = (i == 0) ? -1 : batch[i - 1];
    for (int g = prev + 1; g <= b; ++g) start[g] = i;
    if (i == N - 1)
        for (int g = b + 1; g <= G; ++g) start[g] = N;
}

// ---------------- W-prep (2 kernels, fp32) ----------------
__global__ __launch_bounds__(256) void wprep1(const float* __restrict__ W, const float* __restrict__ bias,
                                              float* __restrict__ W2, float* __restrict__ w1b) {
    int bid = blockIdx.x;
    if (bid < 352) {
        int id = bid * 256 + threadIdx.x;
        if (id >= D * D) return;
        int i = id / D, j = id % D;
        float acc = 0.f;
        #pragma unroll 4
        for (int k = 0; k < D; ++k) acc = fmaf(W[i * D + k], W[k * D + j], acc);
        W2[id] = acc;
    } else {
        int j = threadIdx.x;
        if (j >= D) return;
        float acc = 0.f;
        #pragma unroll 4
        for (int k = 0; k < D; ++k) acc = fmaf(bias[k], W[k * D + j], acc);
        w1b[j] = acc;
    }
}
__global__ __launch_bounds__(256) void wprep2(const float* __restrict__ W2, const float* __restrict__ W,
                                              const float* __restrict__ w1b,
                                              float* __restrict__ W4, float* __restrict__ w2b,
                                              float* __restrict__ w3b) {
    int bid = blockIdx.x;
    if (bid < 352) {
        int id = bid * 256 + threadIdx.x;
        if (id >= D * D) return;
        int i = id / D, j = id % D;
        float acc = 0.f;
        #pragma unroll 4
        for (int k = 0; k < D; ++k) acc = fmaf(W2[i * D + k], W2[k * D + j], acc);
        W4[id] = acc;
    } else if (bid == 352) {
        int j = threadIdx.x;
        if (j >= D) return;
        float acc = 0.f;
        #pragma unroll 4
        for (int k = 0; k < D; ++k) acc = fmaf(w1b[k], W[k * D + j], acc);
        w2b[j] = acc;
    } else {
        int j = threadIdx.x;
        if (j >= D) return;
        float acc = 0.f;
        #pragma unroll 4
        for (int k = 0; k < D; ++k) acc = fmaf(w1b[k], W2[k * D + j], acc);
        w3b[j] = acc;
    }
}

// ---------------- sparse hop (fp16 rows, compact), optional fused scalar-u ----------------
__global__ __launch_bounds__(256) void gather_f16(const half4v* __restrict__ in,
                                                  const int* __restrict__ off,
                                                  const int* __restrict__ csr_src,
                                                  const float* __restrict__ csr_w,
                                                  const float* __restrict__ dinv,
                                                  const float* __restrict__ uin,
                                                  float* __restrict__ uout,
                                                  half4v* __restrict__ out, int N) {
    int idx = blockIdx.x * blockDim.x + threadIdx.x;
    if (idx >= N * DC) return;
    int n = idx / DC, c = idx - n * DC;
    float s = dinv[n]; s = s * s;
    half4v v0 = in[idx];
    float4 acc = make_float4(s * (float)v0[0], s * (float)v0[1], s * (float)v0[2], s * (float)v0[3]);
    const bool dou = (uout != nullptr) && (c == 0);
    float uacc = 0.f;
    if (dou) uacc = s * (uin ? uin[n] : 1.0f);
    int j0 = off[n], j1 = off[n + 1];
    for (int j = j0; j < j1; ++j) {
        int sn = csr_src[j];
        float w = csr_w[j];
        half4v u = in[(size_t)sn * DC + c];
        acc.x += w * (float)u[0]; acc.y += w * (float)u[1];
        acc.z += w * (float)u[2]; acc.w += w * (float)u[3];
        if (dou) uacc += w * (uin ? uin[sn] : 1.0f);
    }
    half4v o;
    o[0] = (_Float16)acc.x; o[1] = (_Float16)acc.y;
    o[2] = (_Float16)acc.z; o[3] = (_Float16)acc.w;
    out[idx] = o;
    if (dou) uout[n] = uacc;
}

// ---------------- fused pool + final GEMM, parallel phase A ----------------
// 512 threads. Phase A: 6 row-groups x 75 chunks (450 active) accumulate partial
// segment sums -> LDS part[6][300]; reduce to row[300]. Depth ~avg_rows/6.
// Phase B: 300 outputs, each a 300-dot with 4 independent FMA chains.
__global__ __launch_bounds__(512) void pool_final(const half4v* __restrict__ g4,
                                                  const float* __restrict__ u1,
                                                  const float* __restrict__ u2,
                                                  const float* __restrict__ u3,
                                                  const int* __restrict__ start,
                                                  const float* __restrict__ W4,
                                                  const float* __restrict__ w1b,
                                                  const float* __restrict__ w2b,
                                                  const float* __restrict__ w3b,
                                                  const float* __restrict__ bias,
                                                  float* __restrict__ out, int G) {
    __shared__ float part[PGRP][D];
    __shared__ float row[D];
    __shared__ float us[4];
    int g = blockIdx.x;
    if (g >= G) return;
    int j0 = start[g], j1 = start[g + 1];
    float inv = (j1 > j0) ? 1.0f / (float)(j1 - j0) : 0.0f;
    int tid = threadIdx.x;

    if (tid < PGRP * DC) {                       // 450 active
        int grp = tid / DC, cc = tid - grp * DC;
        float4 acc = make_float4(0.f, 0.f, 0.f, 0.f);
        for (int n = j0 + grp; n < j1; n += PGRP) {
            half4v v = g4[(size_t)n * DC + cc];
            acc.x += (float)v[0]; acc.y += (float)v[1];
            acc.z += (float)v[2]; acc.w += (float)v[3];
        }
        part[grp][cc * 4 + 0] = acc.x;
        part[grp][cc * 4 + 1] = acc.y;
        part[grp][cc * 4 + 2] = acc.z;
        part[grp][cc * 4 + 3] = acc.w;
    } else if (tid >= 480 && tid <= 482) {
        const float* u = (tid == 480) ? u1 : (tid == 481) ? u2 : u3;
        float acc = 0.f;
        for (int n = j0; n < j1; ++n) acc += u[n];
        us[tid - 480] = acc * inv;
    } else if (tid == 483) {
        us[3] = (j1 > j0) ? 1.0f : 0.0f;
    }
    __syncthreads();
    if (tid < D) {
        float r = 0.f;
        #pragma unroll
        for (int grp = 0; grp < PGRP; ++grp) r += part[grp][tid];
        row[tid] = r * inv;
    }
    __syncthreads();

    float p1 = us[0], p2 = us[1], p3 = us[2], fl = us[3];
    if (tid < D) {
        int j = tid;
        float a0 = 0.f, a1 = 0.f, a2 = 0.f, a3 = 0.f;   // 4 independent chains
        for (int k = 0; k < D; k += 4) {
            a0 = fmaf(row[k + 0], W4[(size_t)(k + 0) * D + j], a0);
            a1 = fmaf(row[k + 1], W4[(size_t)(k + 1) * D + j], a1);
            a2 = fmaf(row[k + 2], W4[(size_t)(k + 2) * D + j], a2);
            a3 = fmaf(row[k + 3], W4[(size_t)(k + 3) * D + j], a3);
        }
        float acc = (a0 + a1) + (a2 + a3);
        out[(size_t)g * D + j] = acc + p1 * w1b[j] + p2 * w2b[j] + p3 * w3b[j] + fl * bias[j];
    }
}

extern "C" void kernel_launch(void* const* d_in, const int* in_sizes, int n_in,
                              void* d_out, int out_size, void* d_ws, size_t ws_size,
                              hipStream_t stream) {
    (void)n_in; (void)ws_size;
    const int*   x     = (const int*)d_in[0];
    const int*   ei    = (const int*)d_in[1];
    const int*   batch = (const int*)d_in[2];
    // d_in[3] = num_hops (fixed 4)
    const float* atomT = (const float*)d_in[4];
    const float* wordT = (const float*)d_in[5];
    const float* W     = (const float*)d_in[6];
    const float* bias  = (const float*)d_in[7];

    const int N = in_sizes[0] / 2;
    const int E = in_sizes[1] / 2;
    const int G = out_size / D;

    const int* src = ei;
    const int* dst = ei + E;

    // workspace layout (16B-aligned starts)
    _Float16* fA16   = (_Float16*)d_ws;                  // N*D fp16
    _Float16* fB16   = fA16 + (size_t)N * D;             // N*D fp16
    float*    dinv   = (float*)(fB16 + (size_t)N * D);   // N
    float*    csr_w  = dinv + N;                         // E
    float*    W2     = csr_w + E;                        // D*D
    float*    W4     = W2 + D * D;                       // D*D
    float*    w1b    = W4 + D * D;                       // D
    float*    w2b    = w1b + D;                          // D
    float*    w3b    = w2b + D;                          // D
    float*    u1     = w3b + D;                          // N
    float*    u2     = u1 + N;                           // N
    float*    u3     = u2 + N;                           // N
    int*      cnt    = (int*)(u3 + N);                   // N
    int*      off    = cnt + N;                          // N+1
    int*      cursor = off + N + 1;                      // N
    int*      csr_src= cursor + N;                       // E
    int*      bsum   = csr_src + E;                      // <=1024
    int*      bbase  = bsum + 1024;                      // <=1024
    int*      start  = bbase + 1024;                     // G+1

    const int B = 256;
    const int ndBlocks = (N * DC + B - 1) / B;
    const int nBlocks  = (N + B - 1) / B;
    const int nbScan   = (N + SCB - 1) / SCB;

    embed_f16<<<ndBlocks, B, 0, stream>>>(x, (const float4*)atomT, (const float4*)wordT, (half4v*)fA16, N);

    hipMemsetAsync(cnt, 0, (size_t)N * sizeof(int), stream);
    cnt_kernel<<<(E + B - 1) / B, B, 0, stream>>>(dst, cnt, E);
    scan1_kernel<<<nbScan, SCB, 0, stream>>>(cnt, off, bsum, dinv, N);
    scan2_kernel<<<1, SCB, 0, stream>>>(bsum, bbase, off, nbScan, N, E);
    scan3_kernel<<<nBlocks, B, 0, stream>>>(off, bbase, cursor, N);
    fill_kernel<<<(E + B - 1) / B, B, 0, stream>>>(src, dst, dinv, cursor, csr_src, csr_w, E);
    seg_start_kernel<<<nBlocks, B, 0, stream>>>(batch, start, N, G);

    wprep1<<<353, B, 0, stream>>>(W, bias, W2, w1b);
    wprep2<<<354, B, 0, stream>>>(W2, W, w1b, W4, w2b, w3b);

    // g_k = A_hat^k h0 (fp16 ping-pong), u_k fused into passes 1-3
    gather_f16<<<ndBlocks, B, 0, stream>>>((const half4v*)fA16, off, csr_src, csr_w, dinv,
                                           nullptr, u1, (half4v*)fB16, N);
    gather_f16<<<ndBlocks, B, 0, stream>>>((const half4v*)fB16, off, csr_src, csr_w, dinv,
                                           u1, u2, (half4v*)fA16, N);
    gather_f16<<<ndBlocks, B, 0, stream>>>((const half4v*)fA16, off, csr_src, csr_w, dinv,
                                           u2, u3, (half4v*)fB16, N);
    gather_f16<<<ndBlocks, B, 0, stream>>>((const half4v*)fB16, off, csr_src, csr_w, dinv,
                                           nullptr, nullptr, (half4v*)fA16, N);

    // fused pool + exact-fp32 small GEMM (parallel phase A)
    pool_final<<<G, 512, 0, stream>>>((const half4v*)fA16, u1, u2, u3, start,
                                      W4, w1b, w2b, w3b, bias, (float*)d_out, G);
}

// Round 19
// 327.834 us; speedup vs baseline: 2.3171x; 1.0369x over previous
//
#include <hip/hip_runtime.h>
#include <hip/hip_fp16.h>

#define D    300
#define DC   75    // D/4 half4 chunks per row
#define SCB  1024  // scan block size
#define PGRP 6     // row-groups in pool phase A (6*75 = 450 active threads)

typedef _Float16 half4v __attribute__((ext_vector_type(4)));

// ---------------- embedding -> fp16 h0 ; fused dst-degree count ----------------
__global__ __launch_bounds__(256) void embed_f16(const int* __restrict__ x,
                                                 const float4* __restrict__ atomT,
                                                 const float4* __restrict__ wordT,
                                                 half4v* __restrict__ h,
                                                 const int* __restrict__ dst, int* __restrict__ cnt,
                                                 int E, int N) {
    int idx = blockIdx.x * blockDim.x + threadIdx.x;
    if (idx < E) atomicAdd(&cnt[dst[idx]], 1);          // fused cnt_kernel
    if (idx >= N * DC) return;
    int n = idx / DC, c = idx - n * DC;
    int a = x[n * 2 + 0];
    int w = x[n * 2 + 1];
    float4 va = atomT[(size_t)a * DC + c];
    float4 vw = wordT[(size_t)w * DC + c];
    half4v o;
    o[0] = (_Float16)(va.x + vw.x);
    o[1] = (_Float16)(va.y + vw.y);
    o[2] = (_Float16)(va.z + vw.z);
    o[3] = (_Float16)(va.w + vw.w);
    h[idx] = o;
}

// ---- scan phase 1 (+ dinv, + fused seg_start) ----
__global__ __launch_bounds__(SCB) void scan1_kernel(const int* __restrict__ cnt,
                                                    int* __restrict__ off, int* __restrict__ bsum,
                                                    float* __restrict__ dinv,
                                                    const int* __restrict__ batch,
                                                    int* __restrict__ start, int G, int N) {
    __shared__ int warp_sums[16];
    const int tid = threadIdx.x;
    const int lane = tid & 63;
    const int wid = tid >> 6;
    int i = blockIdx.x * SCB + tid;
    int v = (i < N) ? cnt[i] : 0;
    if (i < N) {
        dinv[i] = rsqrtf((float)(v + 1));   // +1 self-loop
        int b = batch[i];                   // fused seg_start
        int prev = (i == 0) ? -1 : batch[i - 1];
        for (int g = prev + 1; g <= b; ++g) start[g] = i;
        if (i == N - 1)
            for (int g = b + 1; g <= G; ++g) start[g] = N;
    }
    int s = v;
    #pragma unroll
    for (int d = 1; d < 64; d <<= 1) {
        int t = __shfl_up(s, d, 64);
        if (lane >= d) s += t;
    }
    if (lane == 63) warp_sums[wid] = s;
    __syncthreads();
    if (wid == 0) {
        int ws = (lane < 16) ? warp_sums[lane] : 0;
        #pragma unroll
        for (int d = 1; d < 16; d <<= 1) {
            int t = __shfl_up(ws, d, 64);
            if (lane >= d) ws += t;
        }
        if (lane < 16) warp_sums[lane] = ws;
    }
    __syncthreads();
    int excl = (wid ? warp_sums[wid - 1] : 0) + s - v;
    if (i < N) off[i] = excl;
    if (tid == SCB - 1) bsum[blockIdx.x] = warp_sums[15];
}
__global__ __launch_bounds__(SCB) void scan2_kernel(int* __restrict__ bsum, int* __restrict__ bbase,
                                                    int* __restrict__ off, int nb, int N, int E) {
    __shared__ int warp_sums[16];
    const int tid = threadIdx.x;
    const int lane = tid & 63;
    const int wid = tid >> 6;
    int v = (tid < nb) ? bsum[tid] : 0;
    int s = v;
    #pragma unroll
    for (int d = 1; d < 64; d <<= 1) {
        int t = __shfl_up(s, d, 64);
        if (lane >= d) s += t;
    }
    if (lane == 63) warp_sums[wid] = s;
    __syncthreads();
    if (wid == 0) {
        int ws = (lane < 16) ? warp_sums[lane] : 0;
        #pragma unroll
        for (int d = 1; d < 16; d <<= 1) {
            int t = __shfl_up(ws, d, 64);
            if (lane >= d) ws += t;
        }
        if (lane < 16) warp_sums[lane] = ws;
    }
    __syncthreads();
    if (tid < nb) bbase[tid] = (wid ? warp_sums[wid - 1] : 0) + s - v;
    if (tid == 0) off[N] = E;   // sum of cnt == E identically
}
__global__ __launch_bounds__(256) void scan3_kernel(int* __restrict__ off, const int* __restrict__ bbase,
                                                    int* __restrict__ cursor, int N) {
    int i = blockIdx.x * blockDim.x + threadIdx.x;
    if (i >= N) return;
    int o = off[i] + bbase[i >> 10];
    off[i] = o;
    cursor[i] = o;
}
__global__ __launch_bounds__(256) void fill_kernel(const int* __restrict__ src, const int* __restrict__ dst,
                                                   const float* __restrict__ dinv, int* __restrict__ cursor,
                                                   int* __restrict__ csr_src, float* __restrict__ csr_w, int E) {
    int e = blockIdx.x * blockDim.x + threadIdx.x;
    if (e >= E) return;
    int s = src[e], d = dst[e];
    int slot = atomicAdd(&cursor[d], 1);
    csr_src[slot] = s;
    csr_w[slot] = dinv[s] * dinv[d];
}

// ---------------- W-prep (2 kernels, fp32) ----------------
__global__ __launch_bounds__(256) void wprep1(const float* __restrict__ W, const float* __restrict__ bias,
                                              float* __restrict__ W2, float* __restrict__ w1b) {
    int bid = blockIdx.x;
    if (bid < 352) {
        int id = bid * 256 + threadIdx.x;
        if (id >= D * D) return;
        int i = id / D, j = id % D;
        float acc = 0.f;
        #pragma unroll 4
        for (int k = 0; k < D; ++k) acc = fmaf(W[i * D + k], W[k * D + j], acc);
        W2[id] = acc;
    } else {
        int j = threadIdx.x;
        if (j >= D) return;
        float acc = 0.f;
        #pragma unroll 4
        for (int k = 0; k < D; ++k) acc = fmaf(bias[k], W[k * D + j], acc);
        w1b[j] = acc;
    }
}
__global__ __launch_bounds__(256) void wprep2(const float* __restrict__ W2, const float* __restrict__ W,
                                              const float* __restrict__ w1b,
                                              float* __restrict__ W4, float* __restrict__ w2b,
                                              float* __restrict__ w3b) {
    int bid = blockIdx.x;
    if (bid < 352) {
        int id = bid * 256 + threadIdx.x;
        if (id >= D * D) return;
        int i = id / D, j = id % D;
        float acc = 0.f;
        #pragma unroll 4
        for (int k = 0; k < D; ++k) acc = fmaf(W2[i * D + k], W2[k * D + j], acc);
        W4[id] = acc;
    } else if (bid == 352) {
        int j = threadIdx.x;
        if (j >= D) return;
        float acc = 0.f;
        #pragma unroll 4
        for (int k = 0; k < D; ++k) acc = fmaf(w1b[k], W[k * D + j], acc);
        w2b[j] = acc;
    } else {
        int j = threadIdx.x;
        if (j >= D) return;
        float acc = 0.f;
        #pragma unroll 4
        for (int k = 0; k < D; ++k) acc = fmaf(w1b[k], W2[k * D + j], acc);
        w3b[j] = acc;
    }
}

// ---------------- sparse hop (fp16 rows), grid-stride (G11), fused scalar-u ----------------
__global__ __launch_bounds__(256) void gather_f16(const half4v* __restrict__ in,
                                                  const int* __restrict__ off,
                                                  const int* __restrict__ csr_src,
                                                  const float* __restrict__ csr_w,
                                                  const float* __restrict__ dinv,
                                                  const float* __restrict__ uin,
                                                  float* __restrict__ uout,
                                                  half4v* __restrict__ out, int N) {
    const int stride = gridDim.x * blockDim.x;
    for (int idx = blockIdx.x * blockDim.x + threadIdx.x; idx < N * DC; idx += stride) {
        int n = idx / DC, c = idx - n * DC;
        float s = dinv[n]; s = s * s;
        half4v v0 = in[idx];
        float4 acc = make_float4(s * (float)v0[0], s * (float)v0[1], s * (float)v0[2], s * (float)v0[3]);
        const bool dou = (uout != nullptr) && (c == 0);
        float uacc = 0.f;
        if (dou) uacc = s * (uin ? uin[n] : 1.0f);
        int j0 = off[n], j1 = off[n + 1];
        for (int j = j0; j < j1; ++j) {
            int sn = csr_src[j];
            float w = csr_w[j];
            half4v u = in[(size_t)sn * DC + c];
            acc.x += w * (float)u[0]; acc.y += w * (float)u[1];
            acc.z += w * (float)u[2]; acc.w += w * (float)u[3];
            if (dou) uacc += w * (uin ? uin[sn] : 1.0f);
        }
        half4v o;
        o[0] = (_Float16)acc.x; o[1] = (_Float16)acc.y;
        o[2] = (_Float16)acc.z; o[3] = (_Float16)acc.w;
        out[idx] = o;
        if (dou) uout[n] = uacc;
    }
}

// ---------------- fused hop-4 + pool + final GEMM ----------------
// Phase A: per graph, 6 row-groups x 75 chunks apply A_hat to g3 while pooling
// (fp32 accumulation, no fp16 intermediate for hop 4). Phase B: 300x300 dot.
__global__ __launch_bounds__(512) void pool_final(const half4v* __restrict__ g3,
                                                  const int* __restrict__ off,
                                                  const int* __restrict__ csr_src,
                                                  const float* __restrict__ csr_w,
                                                  const float* __restrict__ dinv,
                                                  const float* __restrict__ u1,
                                                  const float* __restrict__ u2,
                                                  const float* __restrict__ u3,
                                                  const int* __restrict__ start,
                                                  const float* __restrict__ W4,
                                                  const float* __restrict__ w1b,
                                                  const float* __restrict__ w2b,
                                                  const float* __restrict__ w3b,
                                                  const float* __restrict__ bias,
                                                  float* __restrict__ out, int G) {
    __shared__ float part[PGRP][D];
    __shared__ float row[D];
    __shared__ float us[4];
    int g = blockIdx.x;
    if (g >= G) return;
    int j0 = start[g], j1 = start[g + 1];
    float inv = (j1 > j0) ? 1.0f / (float)(j1 - j0) : 0.0f;
    int tid = threadIdx.x;

    if (tid < PGRP * DC) {                       // 450 active: hop-4 + pool
        int grp = tid / DC, cc = tid - grp * DC;
        float4 acc = make_float4(0.f, 0.f, 0.f, 0.f);
        for (int n = j0 + grp; n < j1; n += PGRP) {
            float s = dinv[n]; s = s * s;
            half4v v = g3[(size_t)n * DC + cc];
            acc.x += s * (float)v[0]; acc.y += s * (float)v[1];
            acc.z += s * (float)v[2]; acc.w += s * (float)v[3];
            int e0 = off[n], e1 = off[n + 1];
            for (int j = e0; j < e1; ++j) {
                int sn = csr_src[j];
                float w = csr_w[j];
                half4v u = g3[(size_t)sn * DC + cc];
                acc.x += w * (float)u[0]; acc.y += w * (float)u[1];
                acc.z += w * (float)u[2]; acc.w += w * (float)u[3];
            }
        }
        part[grp][cc * 4 + 0] = acc.x;
        part[grp][cc * 4 + 1] = acc.y;
        part[grp][cc * 4 + 2] = acc.z;
        part[grp][cc * 4 + 3] = acc.w;
    } else if (tid >= 480 && tid <= 482) {
        const float* u = (tid == 480) ? u1 : (tid == 481) ? u2 : u3;
        float acc = 0.f;
        for (int n = j0; n < j1; ++n) acc += u[n];
        us[tid - 480] = acc * inv;
    } else if (tid == 483) {
        us[3] = (j1 > j0) ? 1.0f : 0.0f;
    }
    __syncthreads();
    if (tid < D) {
        float r = 0.f;
        #pragma unroll
        for (int grp = 0; grp < PGRP; ++grp) r += part[grp][tid];
        row[tid] = r * inv;
    }
    __syncthreads();

    float p1 = us[0], p2 = us[1], p3 = us[2], fl = us[3];
    if (tid < D) {
        int j = tid;
        float a0 = 0.f, a1 = 0.f, a2 = 0.f, a3 = 0.f;   // 4 independent chains
        for (int k = 0; k < D; k += 4) {
            a0 = fmaf(row[k + 0], W4[(size_t)(k + 0) * D + j], a0);
            a1 = fmaf(row[k + 1], W4[(size_t)(k + 1) * D + j], a1);
            a2 = fmaf(row[k + 2], W4[(size_t)(k + 2) * D + j], a2);
            a3 = fmaf(row[k + 3], W4[(size_t)(k + 3) * D + j], a3);
        }
        float acc = (a0 + a1) + (a2 + a3);
        out[(size_t)g * D + j] = acc + p1 * w1b[j] + p2 * w2b[j] + p3 * w3b[j] + fl * bias[j];
    }
}

extern "C" void kernel_launch(void* const* d_in, const int* in_sizes, int n_in,
                              void* d_out, int out_size, void* d_ws, size_t ws_size,
                              hipStream_t stream) {
    (void)n_in; (void)ws_size;
    const int*   x     = (const int*)d_in[0];
    const int*   ei    = (const int*)d_in[1];
    const int*   batch = (const int*)d_in[2];
    // d_in[3] = num_hops (fixed 4)
    const float* atomT = (const float*)d_in[4];
    const float* wordT = (const float*)d_in[5];
    const float* W     = (const float*)d_in[6];
    const float* bias  = (const float*)d_in[7];

    const int N = in_sizes[0] / 2;
    const int E = in_sizes[1] / 2;
    const int G = out_size / D;

    const int* src = ei;
    const int* dst = ei + E;

    // workspace layout (16B-aligned starts)
    _Float16* fA16   = (_Float16*)d_ws;                  // N*D fp16
    _Float16* fB16   = fA16 + (size_t)N * D;             // N*D fp16
    float*    dinv   = (float*)(fB16 + (size_t)N * D);   // N
    float*    csr_w  = dinv + N;                         // E
    float*    W2     = csr_w + E;                        // D*D
    float*    W4     = W2 + D * D;                       // D*D
    float*    w1b    = W4 + D * D;                       // D
    float*    w2b    = w1b + D;                          // D
    float*    w3b    = w2b + D;                          // D
    float*    u1     = w3b + D;                          // N
    float*    u2     = u1 + N;                           // N
    float*    u3     = u2 + N;                           // N
    int*      cnt    = (int*)(u3 + N);                   // N
    int*      off    = cnt + N;                          // N+1
    int*      cursor = off + N + 1;                      // N
    int*      csr_src= cursor + N;                       // E
    int*      bsum   = csr_src + E;                      // <=1024
    int*      bbase  = bsum + 1024;                      // <=1024
    int*      start  = bbase + 1024;                     // G+1

    const int B = 256;
    const int ndBlocks = (N * DC + B - 1) / B;
    const int nBlocks  = (N + B - 1) / B;
    const int nbScan   = (N + SCB - 1) / SCB;
    const int gatherGrid = 2048;                          // G11: 8 blocks/CU, grid-stride

    hipMemsetAsync(cnt, 0, (size_t)N * sizeof(int), stream);
    embed_f16<<<ndBlocks, B, 0, stream>>>(x, (const float4*)atomT, (const float4*)wordT,
                                          (half4v*)fA16, dst, cnt, E, N);
    scan1_kernel<<<nbScan, SCB, 0, stream>>>(cnt, off, bsum, dinv, batch, start, G, N);
    scan2_kernel<<<1, SCB, 0, stream>>>(bsum, bbase, off, nbScan, N, E);
    scan3_kernel<<<nBlocks, B, 0, stream>>>(off, bbase, cursor, N);
    fill_kernel<<<(E + B - 1) / B, B, 0, stream>>>(src, dst, dinv, cursor, csr_src, csr_w, E);

    wprep1<<<353, B, 0, stream>>>(W, bias, W2, w1b);
    wprep2<<<354, B, 0, stream>>>(W2, W, w1b, W4, w2b, w3b);

    // g_k = A_hat^k h0, k=1..3 (fp16 ping-pong), u_k fused
    gather_f16<<<gatherGrid, B, 0, stream>>>((const half4v*)fA16, off, csr_src, csr_w, dinv,
                                             nullptr, u1, (half4v*)fB16, N);
    gather_f16<<<gatherGrid, B, 0, stream>>>((const half4v*)fB16, off, csr_src, csr_w, dinv,
                                             u1, u2, (half4v*)fA16, N);
    gather_f16<<<gatherGrid, B, 0, stream>>>((const half4v*)fA16, off, csr_src, csr_w, dinv,
                                             u2, u3, (half4v*)fB16, N);

    // hop 4 fused into pool (fp32 accumulation) + exact-fp32 small GEMM
    pool_final<<<G, 512, 0, stream>>>((const half4v*)fB16, off, csr_src, csr_w, dinv,
                                      u1, u2, u3, start, W4, w1b, w2b, w3b, bias,
                                      (float*)d_out, G);
}

// Round 20
// 327.196 us; speedup vs baseline: 2.3216x; 1.0019x over previous
//
#include <hip/hip_runtime.h>
#include <hip/hip_fp16.h>

#define D    300
#define DC   75    // D/4 half4 chunks per row
#define SCB  1024  // scan block size
#define PGRP 6     // row-groups in pool phase A (6*75 = 450 active threads)

typedef _Float16 half4v __attribute__((ext_vector_type(4)));

// ---------------- embedding -> fp16 h0 ; fused dst-degree count ----------------
__global__ __launch_bounds__(256) void embed_f16(const int* __restrict__ x,
                                                 const float4* __restrict__ atomT,
                                                 const float4* __restrict__ wordT,
                                                 half4v* __restrict__ h,
                                                 const int* __restrict__ dst, int* __restrict__ cnt,
                                                 int E, int N) {
    int idx = blockIdx.x * blockDim.x + threadIdx.x;
    if (idx < E) atomicAdd(&cnt[dst[idx]], 1);          // fused cnt_kernel
    if (idx >= N * DC) return;
    int n = idx / DC, c = idx - n * DC;
    int a = x[n * 2 + 0];
    int w = x[n * 2 + 1];
    float4 va = atomT[(size_t)a * DC + c];
    float4 vw = wordT[(size_t)w * DC + c];
    half4v o;
    o[0] = (_Float16)(va.x + vw.x);
    o[1] = (_Float16)(va.y + vw.y);
    o[2] = (_Float16)(va.z + vw.z);
    o[3] = (_Float16)(va.w + vw.w);
    h[idx] = o;
}

// ---- scan phase 1: block-local exclusive scan -> off AND cursor (+ dinv, seg_start) ----
__global__ __launch_bounds__(SCB) void scan1_kernel(const int* __restrict__ cnt,
                                                    int* __restrict__ off, int* __restrict__ cursor,
                                                    int* __restrict__ bsum,
                                                    float* __restrict__ dinv,
                                                    const int* __restrict__ batch,
                                                    int* __restrict__ start, int G, int N) {
    __shared__ int warp_sums[16];
    const int tid = threadIdx.x;
    const int lane = tid & 63;
    const int wid = tid >> 6;
    int i = blockIdx.x * SCB + tid;
    int v = (i < N) ? cnt[i] : 0;
    if (i < N) {
        dinv[i] = rsqrtf((float)(v + 1));   // +1 self-loop
        int b = batch[i];                   // fused seg_start
        int prev = (i == 0) ? -1 : batch[i - 1];
        for (int g = prev + 1; g <= b; ++g) start[g] = i;
        if (i == N - 1)
            for (int g = b + 1; g <= G; ++g) start[g] = N;
    }
    int s = v;
    #pragma unroll
    for (int d = 1; d < 64; d <<= 1) {
        int t = __shfl_up(s, d, 64);
        if (lane >= d) s += t;
    }
    if (lane == 63) warp_sums[wid] = s;
    __syncthreads();
    if (wid == 0) {
        int ws = (lane < 16) ? warp_sums[lane] : 0;
        #pragma unroll
        for (int d = 1; d < 16; d <<= 1) {
            int t = __shfl_up(ws, d, 64);
            if (lane >= d) ws += t;
        }
        if (lane < 16) warp_sums[lane] = ws;
    }
    __syncthreads();
    int excl = (wid ? warp_sums[wid - 1] : 0) + s - v;
    if (i < N) { off[i] = excl; cursor[i] = excl; }   // block-LOCAL offsets
    if (tid == SCB - 1) bsum[blockIdx.x] = warp_sums[15];
}
// ---- scan phase 2: scan block sums -> bbase; off[N] = local form of E ----
__global__ __launch_bounds__(SCB) void scan2_kernel(const int* __restrict__ bsum, int* __restrict__ bbase,
                                                    int* __restrict__ off, int nb, int N) {
    __shared__ int warp_sums[16];
    const int tid = threadIdx.x;
    const int lane = tid & 63;
    const int wid = tid >> 6;
    int v = (tid < nb) ? bsum[tid] : 0;
    int s = v;
    #pragma unroll
    for (int d = 1; d < 64; d <<= 1) {
        int t = __shfl_up(s, d, 64);
        if (lane >= d) s += t;
    }
    if (lane == 63) warp_sums[wid] = s;
    __syncthreads();
    if (wid == 0) {
        int ws = (lane < 16) ? warp_sums[lane] : 0;
        #pragma unroll
        for (int d = 1; d < 16; d <<= 1) {
            int t = __shfl_up(ws, d, 64);
            if (lane >= d) ws += t;
        }
        if (lane < 16) warp_sums[lane] = ws;
    }
    __syncthreads();
    if (tid < nb) bbase[tid] = (wid ? warp_sums[wid - 1] : 0) + s - v;
    // off[N] + bbase[N>>10] must equal E; N>>10 == nb-1, bbase[nb-1] = E - bsum[nb-1]
    if (tid == 0) off[N] = bsum[nb - 1];
}
__global__ __launch_bounds__(256) void fill_kernel(const int* __restrict__ src, const int* __restrict__ dst,
                                                   const float* __restrict__ dinv, int* __restrict__ cursor,
                                                   const int* __restrict__ bbase,
                                                   int* __restrict__ csr_src, float* __restrict__ csr_w, int E) {
    int e = blockIdx.x * blockDim.x + threadIdx.x;
    if (e >= E) return;
    int s = src[e], d = dst[e];
    int slot = atomicAdd(&cursor[d], 1) + bbase[d >> 10];
    csr_src[slot] = s;
    csr_w[slot] = dinv[s] * dinv[d];
}

// ---------------- W-prep (2 kernels, fp32) ----------------
__global__ __launch_bounds__(256) void wprep1(const float* __restrict__ W, const float* __restrict__ bias,
                                              float* __restrict__ W2, float* __restrict__ w1b) {
    int bid = blockIdx.x;
    if (bid < 352) {
        int id = bid * 256 + threadIdx.x;
        if (id >= D * D) return;
        int i = id / D, j = id % D;
        float acc = 0.f;
        #pragma unroll 4
        for (int k = 0; k < D; ++k) acc = fmaf(W[i * D + k], W[k * D + j], acc);
        W2[id] = acc;
    } else {
        int j = threadIdx.x;
        if (j >= D) return;
        float acc = 0.f;
        #pragma unroll 4
        for (int k = 0; k < D; ++k) acc = fmaf(bias[k], W[k * D + j], acc);
        w1b[j] = acc;
    }
}
__global__ __launch_bounds__(256) void wprep2(const float* __restrict__ W2, const float* __restrict__ W,
                                              const float* __restrict__ w1b,
                                              float* __restrict__ W4, float* __restrict__ w2b,
                                              float* __restrict__ w3b) {
    int bid = blockIdx.x;
    if (bid < 352) {
        int id = bid * 256 + threadIdx.x;
        if (id >= D * D) return;
        int i = id / D, j = id % D;
        float acc = 0.f;
        #pragma unroll 4
        for (int k = 0; k < D; ++k) acc = fmaf(W2[i * D + k], W2[k * D + j], acc);
        W4[id] = acc;
    } else if (bid == 352) {
        int j = threadIdx.x;
        if (j >= D) return;
        float acc = 0.f;
        #pragma unroll 4
        for (int k = 0; k < D; ++k) acc = fmaf(w1b[k], W[k * D + j], acc);
        w2b[j] = acc;
    } else {
        int j = threadIdx.x;
        if (j >= D) return;
        float acc = 0.f;
        #pragma unroll 4
        for (int k = 0; k < D; ++k) acc = fmaf(w1b[k], W2[k * D + j], acc);
        w3b[j] = acc;
    }
}

// ---------------- sparse hop (fp16 rows), grid-stride, fused scalar-u ----------------
__global__ __launch_bounds__(256) void gather_f16(const half4v* __restrict__ in,
                                                  const int* __restrict__ off,
                                                  const int* __restrict__ bbase,
                                                  const int* __restrict__ csr_src,
                                                  const float* __restrict__ csr_w,
                                                  const float* __restrict__ dinv,
                                                  const float* __restrict__ uin,
                                                  float* __restrict__ uout,
                                                  half4v* __restrict__ out, int N) {
    const int stride = gridDim.x * blockDim.x;
    for (int idx = blockIdx.x * blockDim.x + threadIdx.x; idx < N * DC; idx += stride) {
        int n = idx / DC, c = idx - n * DC;
        float s = dinv[n]; s = s * s;
        half4v v0 = in[idx];
        float4 acc = make_float4(s * (float)v0[0], s * (float)v0[1], s * (float)v0[2], s * (float)v0[3]);
        const bool dou = (uout != nullptr) && (c == 0);
        float uacc = 0.f;
        if (dou) uacc = s * (uin ? uin[n] : 1.0f);
        int j0 = off[n] + bbase[n >> 10];
        int j1 = off[n + 1] + bbase[(n + 1) >> 10];
        for (int j = j0; j < j1; ++j) {
            int sn = csr_src[j];
            float w = csr_w[j];
            half4v u = in[(size_t)sn * DC + c];
            acc.x += w * (float)u[0]; acc.y += w * (float)u[1];
            acc.z += w * (float)u[2]; acc.w += w * (float)u[3];
            if (dou) uacc += w * (uin ? uin[sn] : 1.0f);
        }
        half4v o;
        o[0] = (_Float16)acc.x; o[1] = (_Float16)acc.y;
        o[2] = (_Float16)acc.z; o[3] = (_Float16)acc.w;
        out[idx] = o;
        if (dou) uout[n] = uacc;
    }
}

// ---------------- fused hop-4 + pool + final GEMM ----------------
__global__ __launch_bounds__(512) void pool_final(const half4v* __restrict__ g3,
                                                  const int* __restrict__ off,
                                                  const int* __restrict__ bbase,
                                                  const int* __restrict__ csr_src,
                                                  const float* __restrict__ csr_w,
                                                  const float* __restrict__ dinv,
                                                  const float* __restrict__ u1,
                                                  const float* __restrict__ u2,
                                                  const float* __restrict__ u3,
                                                  const int* __restrict__ start,
                                                  const float* __restrict__ W4,
                                                  const float* __restrict__ w1b,
                                                  const float* __restrict__ w2b,
                                                  const float* __restrict__ w3b,
                                                  const float* __restrict__ bias,
                                                  float* __restrict__ out, int G) {
    __shared__ float part[PGRP][D];
    __shared__ float row[D];
    __shared__ float us[4];
    int g = blockIdx.x;
    if (g >= G) return;
    int j0 = start[g], j1 = start[g + 1];
    float inv = (j1 > j0) ? 1.0f / (float)(j1 - j0) : 0.0f;
    int tid = threadIdx.x;

    if (tid < PGRP * DC) {                       // 450 active: hop-4 + pool
        int grp = tid / DC, cc = tid - grp * DC;
        float4 acc = make_float4(0.f, 0.f, 0.f, 0.f);
        for (int n = j0 + grp; n < j1; n += PGRP) {
            float s = dinv[n]; s = s * s;
            half4v v = g3[(size_t)n * DC + cc];
            acc.x += s * (float)v[0]; acc.y += s * (float)v[1];
            acc.z += s * (float)v[2]; acc.w += s * (float)v[3];
            int e0 = off[n] + bbase[n >> 10];
            int e1 = off[n + 1] + bbase[(n + 1) >> 10];
            for (int j = e0; j < e1; ++j) {
                int sn = csr_src[j];
                float w = csr_w[j];
                half4v u = g3[(size_t)sn * DC + cc];
                acc.x += w * (float)u[0]; acc.y += w * (float)u[1];
                acc.z += w * (float)u[2]; acc.w += w * (float)u[3];
            }
        }
        part[grp][cc * 4 + 0] = acc.x;
        part[grp][cc * 4 + 1] = acc.y;
        part[grp][cc * 4 + 2] = acc.z;
        part[grp][cc * 4 + 3] = acc.w;
    } else if (tid >= 480 && tid <= 482) {
        const float* u = (tid == 480) ? u1 : (tid == 481) ? u2 : u3;
        float acc = 0.f;
        for (int n = j0; n < j1; ++n) acc += u[n];
        us[tid - 480] = acc * inv;
    } else if (tid == 483) {
        us[3] = (j1 > j0) ? 1.0f : 0.0f;
    }
    __syncthreads();
    if (tid < D) {
        float r = 0.f;
        #pragma unroll
        for (int grp = 0; grp < PGRP; ++grp) r += part[grp][tid];
        row[tid] = r * inv;
    }
    __syncthreads();

    float p1 = us[0], p2 = us[1], p3 = us[2], fl = us[3];
    if (tid < D) {
        int j = tid;
        float a0 = 0.f, a1 = 0.f, a2 = 0.f, a3 = 0.f;   // 4 independent chains
        for (int k = 0; k < D; k += 4) {
            a0 = fmaf(row[k + 0], W4[(size_t)(k + 0) * D + j], a0);
            a1 = fmaf(row[k + 1], W4[(size_t)(k + 1) * D + j], a1);
            a2 = fmaf(row[k + 2], W4[(size_t)(k + 2) * D + j], a2);
            a3 = fmaf(row[k + 3], W4[(size_t)(k + 3) * D + j], a3);
        }
        float acc = (a0 + a1) + (a2 + a3);
        out[(size_t)g * D + j] = acc + p1 * w1b[j] + p2 * w2b[j] + p3 * w3b[j] + fl * bias[j];
    }
}

extern "C" void kernel_launch(void* const* d_in, const int* in_sizes, int n_in,
                              void* d_out, int out_size, void* d_ws, size_t ws_size,
                              hipStream_t stream) {
    (void)n_in; (void)ws_size;
    const int*   x     = (const int*)d_in[0];
    const int*   ei    = (const int*)d_in[1];
    const int*   batch = (const int*)d_in[2];
    // d_in[3] = num_hops (fixed 4)
    const float* atomT = (const float*)d_in[4];
    const float* wordT = (const float*)d_in[5];
    const float* W     = (const float*)d_in[6];
    const float* bias  = (const float*)d_in[7];

    const int N = in_sizes[0] / 2;
    const int E = in_sizes[1] / 2;
    const int G = out_size / D;

    const int* src = ei;
    const int* dst = ei + E;

    // workspace layout (16B-aligned starts)
    _Float16* fA16   = (_Float16*)d_ws;                  // N*D fp16
    _Float16* fB16   = fA16 + (size_t)N * D;             // N*D fp16
    float*    dinv   = (float*)(fB16 + (size_t)N * D);   // N
    float*    csr_w  = dinv + N;                         // E
    float*    W2     = csr_w + E;                        // D*D
    float*    W4     = W2 + D * D;                       // D*D
    float*    w1b    = W4 + D * D;                       // D
    float*    w2b    = w1b + D;                          // D
    float*    w3b    = w2b + D;                          // D
    float*    u1     = w3b + D;                          // N
    float*    u2     = u1 + N;                           // N
    float*    u3     = u2 + N;                           // N
    int*      cnt    = (int*)(u3 + N);                   // N
    int*      off    = cnt + N;                          // N+1
    int*      cursor = off + N + 1;                      // N
    int*      csr_src= cursor + N;                       // E
    int*      bsum   = csr_src + E;                      // <=1024
    int*      bbase  = bsum + 1024;                      // <=1024
    int*      start  = bbase + 1024;                     // G+1

    const int B = 256;
    const int ndBlocks = (N * DC + B - 1) / B;
    const int nbScan   = (N + SCB - 1) / SCB;
    const int gatherGrid = 2048;

    hipMemsetAsync(cnt, 0, (size_t)N * sizeof(int), stream);
    embed_f16<<<ndBlocks, B, 0, stream>>>(x, (const float4*)atomT, (const float4*)wordT,
                                          (half4v*)fA16, dst, cnt, E, N);
    scan1_kernel<<<nbScan, SCB, 0, stream>>>(cnt, off, cursor, bsum, dinv, batch, start, G, N);
    scan2_kernel<<<1, SCB, 0, stream>>>(bsum, bbase, off, nbScan, N);
    fill_kernel<<<(E + B - 1) / B, B, 0, stream>>>(src, dst, dinv, cursor, bbase, csr_src, csr_w, E);

    wprep1<<<353, B, 0, stream>>>(W, bias, W2, w1b);
    wprep2<<<354, B, 0, stream>>>(W2, W, w1b, W4, w2b, w3b);

    // g_k = A_hat^k h0, k=1..3 (fp16 ping-pong), u_k fused
    gather_f16<<<gatherGrid, B, 0, stream>>>((const half4v*)fA16, off, bbase, csr_src, csr_w, dinv,
                                             nullptr, u1, (half4v*)fB16, N);
    gather_f16<<<gatherGrid, B, 0, stream>>>((const half4v*)fB16, off, bbase, csr_src, csr_w, dinv,
                                             u1, u2, (half4v*)fA16, N);
    gather_f16<<<gatherGrid, B, 0, stream>>>((const half4v*)fA16, off, bbase, csr_src, csr_w, dinv,
                                             u2, u3, (half4v*)fB16, N);

    // hop 4 fused into pool (fp32 accumulation) + exact-fp32 small GEMM
    pool_final<<<G, 512, 0, stream>>>((const half4v*)fB16, off, bbase, csr_src, csr_w, dinv,
                                      u1, u2, u3, start, W4, w1b, w2b, w3b, bias,
                                      (float*)d_out, G);
}